// Round 7
// baseline (254.475 us; speedup 1.0000x reference)
//
#include <hip/hip_runtime.h>
#include <stdint.h>

// Attention B=2,H=16,S=2048,D=64 fp32. Round 13 (2nd resubmit after infra
// timeouts): triple-buffered wave-private staging with stage AT TOP of body
// -> lgkm drain deleted, vmcnt waits free, and (unlike r12) register
// pressure byte-identical to the known-good r10.
//
// r12 post-mortem: stage-at-END put the 4 DMA address computations live at
// the MFMA section -> peak pressure +~10 regs -> per-iteration spill of a
// few regs (FETCH 77MB/WRITE 95MB), and each spill reload's vmcnt(0)-precise
// wait drained the DMA queue every iteration -> 132us, both pipes halved.
// Law (3 spills in 4 rounds): only touch the LOW-pressure top of the body.
//
// This round keeps r10's body order and register layout exactly, changing
// only the buffering math:
//  - 3 buffers/wave (3 x [2KB K + 2KB V] = 12KB/wave, 48KB/block);
//    tile t lives in buf t%3.
//  - Top of iter kt: stage(kt+2) into buf (kt+2)%3 == (kt-1)%3, the buffer
//    read in iter kt-1 -- those ds_reads were consumed by iter kt-1's MFMAs
//    (compiler lgkm operand-waits already retired) => WAR-safe with NO lgkm
//    wait. r10's per-iter lgkmcnt(0) drain (~120cyc) is DELETED, not
//    replaced.
//  - Then s_waitcnt vmcnt(8): outstanding = tiles kt+1,kt+2; tile kt's DMA
//    was issued 2 iterations (~1200cyc) ago -> wait nearly always already
//    satisfied (HBM worst ~900cyc).
//  - Then ds_read fragments; QK -> exp -> PV. No barrier until epilogue.
//  Tail: kt=30 vmcnt(4), kt=31 vmcnt(0).
//
// Occupancy: LDS 48KB -> 3 blocks/CU (reg-limited at 3 anyway). Same as r10,
// so the deleted waits are pure win.
//
// Per-wave LDS layouts (unchanged):
//   K [16 rows=keys][8 slots of 16B]: row r slot s holds d-octet s^(r&7)
//   V [64 rows=d][2 slots of 16B]:    row d slot s holds key-chunk s^((d>>2)&1)
// Swizzles applied on the GLOBAL gather side of the DMA; fragment reads are
// <=2-way banked (free, m136).

typedef _Float16 f16;
typedef __attribute__((ext_vector_type(4))) _Float16 f16x4;
typedef __attribute__((ext_vector_type(8))) _Float16 f16x8;
typedef __attribute__((ext_vector_type(4))) float f32x4;

constexpr int Bc = 2, Hc = 16, Sc = 2048, Dc = 64;
constexpr size_t NE = (size_t)Bc * Hc * Sc * Dc;

__device__ inline void gld_lds16(const f16* g, f16* l) {
  __builtin_amdgcn_global_load_lds(
      (const __attribute__((address_space(1))) unsigned int*)g,
      (__attribute__((address_space(3))) unsigned int*)l, 16, 0, 0);
}

// ---------------- prep: K*scale -> f16; V -> f16 transposed (unchanged) ---
__global__ __launch_bounds__(256)
void prep(const float* __restrict__ kp, const float* __restrict__ vp,
          const float* __restrict__ temp,
          f16* __restrict__ kh, f16* __restrict__ vt) {
  const int tid = threadIdx.x;
  const int bh = blockIdx.x & 31;
  const int st = blockIdx.x >> 5;
  const float ksc = 1.44269504088896340736f / (temp[0] * 8.0f);

  const size_t base = (size_t)bh * Sc * Dc + (size_t)st * 64 * Dc;
  const float* kg = kp + base;
  f16* khg = kh + base;
#pragma unroll
  for (int i = 0; i < 4; ++i) {
    int f = tid + (i << 8);
    f32x4 a = *(const f32x4*)(kg + f * 4);
    *(f16x4*)(khg + f * 4) = (f16x4){(f16)(a.x * ksc), (f16)(a.y * ksc),
                                     (f16)(a.z * ksc), (f16)(a.w * ksc)};
  }
  const int sb = tid & 15, db = tid >> 4;
  const float* vg = vp + base;
  f32x4 r0 = *(const f32x4*)(vg + (4 * sb + 0) * Dc + 4 * db);
  f32x4 r1 = *(const f32x4*)(vg + (4 * sb + 1) * Dc + 4 * db);
  f32x4 r2 = *(const f32x4*)(vg + (4 * sb + 2) * Dc + 4 * db);
  f32x4 r3 = *(const f32x4*)(vg + (4 * sb + 3) * Dc + 4 * db);
  f16* vtg = vt + (size_t)bh * Dc * Sc + (size_t)st * 64 + 4 * sb;
  *(f16x4*)(vtg + (size_t)(4 * db + 0) * Sc) = (f16x4){(f16)r0.x, (f16)r1.x, (f16)r2.x, (f16)r3.x};
  *(f16x4*)(vtg + (size_t)(4 * db + 1) * Sc) = (f16x4){(f16)r0.y, (f16)r1.y, (f16)r2.y, (f16)r3.y};
  *(f16x4*)(vtg + (size_t)(4 * db + 2) * Sc) = (f16x4){(f16)r0.z, (f16)r1.z, (f16)r2.z, (f16)r3.z};
  *(f16x4*)(vtg + (size_t)(4 * db + 3) * Sc) = (f16x4){(f16)r0.w, (f16)r1.w, (f16)r2.w, (f16)r3.w};
}

// ---------------- fa13: triple-buffer, stage-at-top, no lgkm drain --------
__global__ __launch_bounds__(256, 3)
void fa13(const float* __restrict__ qp, const f16* __restrict__ kh,
          const f16* __restrict__ vt, float* __restrict__ out) {
  // union: staging (4 waves x 3 bufs x [2KB K + 2KB V] = 48KB) /
  //        epilogue (2x 64x66 f32 = 33792B)
  __shared__ __align__(16) char smem[49152];
  __shared__ float Lred[4][64];

  const int tid = threadIdx.x, lane = tid & 63, w = tid >> 6;
  const int lq = lane & 15, qd = lane >> 4;
  const int L = blockIdx.x;
  const int bh = L & 31;                   // blockIdx%8 == bh%8 (XCD-affine)
  const int qt = L >> 5;

  const size_t base = (size_t)bh * Sc * Dc;

  // per-wave staging buffers (f16 units): 3 bufs x 1024 f16 per region
  f16* Kw = (f16*)smem + w * 3072;                 // [3][1024]
  f16* Vw = (f16*)(smem + 24576) + w * 3072;       // [3][1024]

  // ---- staging gather addresses (swizzle on the global side) ----
  const int oct = (lane & 7) ^ ((lane >> 3) & 7);
  const f16* kg0 = kh + base + (size_t)(16 * w + (lane >> 3)) * 64 + oct * 8;
  const f16* kg1 = kg0 + 8 * 64;
  const int vd = lane >> 1;
  const int vc = (lane & 1) ^ ((lane >> 3) & 1);
  const f16* vg0 = vt + (size_t)bh * Dc * Sc + (size_t)vd * Sc + 16 * w + vc * 8;
  const f16* vg1 = vg0 + (size_t)32 * Sc;

  auto stage = [&](int kt, int b) {
    gld_lds16(kg0 + (size_t)kt * 4096, Kw + b * 1024);
    gld_lds16(kg1 + (size_t)kt * 4096, Kw + b * 1024 + 512);
    gld_lds16(vg0 + kt * 64, Vw + b * 1024);
    gld_lds16(vg1 + kt * 64, Vw + b * 1024 + 512);
  };

  // ---- fragment LDS offsets (f16 units, constant per lane) ----
  const int koff0 = lq * 64 + ((qd) ^ (lq & 7)) * 8;
  const int koff1 = lq * 64 + ((4 + qd) ^ (lq & 7)) * 8;
  int voff[4];
#pragma unroll
  for (int dt = 0; dt < 4; ++dt)
    voff[dt] = (16 * dt + lq) * 16 + (((qd >> 1) ^ ((lq >> 2) & 1)) << 3) +
               (qd & 1) * 4;

  // ---- Q B-fragments (one-time packed cvt) ----
  const float* qg = qp + base + (size_t)qt * 64 * Dc;
  f16x8 Qf[4][2];
#pragma unroll
  for (int nt = 0; nt < 4; ++nt)
#pragma unroll
    for (int kc = 0; kc < 2; ++kc) {
      const float* p = qg + (16 * nt + lq) * Dc + 32 * kc + 8 * qd;
      f32x4 a = *(const f32x4*)p;
      f32x4 b = *(const f32x4*)(p + 4);
      auto p0 = __builtin_amdgcn_cvt_pkrtz(a.x, a.y);
      auto p1 = __builtin_amdgcn_cvt_pkrtz(a.z, a.w);
      auto p2 = __builtin_amdgcn_cvt_pkrtz(b.x, b.y);
      auto p3 = __builtin_amdgcn_cvt_pkrtz(b.z, b.w);
      f16x8 qf;
      ((decltype(p0)*)&qf)[0] = p0;
      ((decltype(p0)*)&qf)[1] = p1;
      ((decltype(p0)*)&qf)[2] = p2;
      ((decltype(p0)*)&qf)[3] = p3;
      Qf[nt][kc] = qf;
    }

  // pinned zero accumulator source (avoids 16 v_movs/iter re-zeroing C)
  float z0 = 0.f, z1 = 0.f, z2 = 0.f, z3 = 0.f;
  asm volatile("" : "+v"(z0), "+v"(z1), "+v"(z2), "+v"(z3));
  const f32x4 Zc = (f32x4){z0, z1, z2, z3};

  f32x4 Oa[4][4];
  float ls[4];
#pragma unroll
  for (int nt = 0; nt < 4; ++nt) {
    ls[nt] = 0.f;
#pragma unroll
    for (int dt = 0; dt < 4; ++dt) Oa[nt][dt] = (f32x4){0.f, 0.f, 0.f, 0.f};
  }

  stage(0, 0);
  stage(1, 1);

  // Body kt: stage(kt+2 -> buf (kt+2)%3, WAR-safe: that buffer's reads were
  // consumed by iter kt-1's MFMAs); vmcnt(WN) [tile kt landed, issued 2
  // iters ago]; ds_read fragments from buf kt%3; QK -> exp -> PV.
#define FA_BODY(BUF, SBUF, STGKT, WN)                                         \
  {                                                                           \
    if ((STGKT) < 32) stage((STGKT), (SBUF));                                 \
    asm volatile("s_waitcnt vmcnt(" WN ")" ::: "memory");                     \
    const f16* KB = Kw + (BUF) * 1024;                                        \
    const f16* VB = Vw + (BUF) * 1024;                                        \
    f16x8 K0 = *(const f16x8*)(KB + koff0);                                   \
    f16x8 K1 = *(const f16x8*)(KB + koff1);                                   \
    f16x4 Vf[4];                                                              \
    _Pragma("unroll")                                                         \
    for (int dt = 0; dt < 4; ++dt) Vf[dt] = *(const f16x4*)(VB + voff[dt]);   \
    f32x4 St[4];                                                              \
    _Pragma("unroll")                                                         \
    for (int nt = 0; nt < 4; ++nt) {                                          \
      f32x4 a = __builtin_amdgcn_mfma_f32_16x16x32_f16(K0, Qf[nt][0], Zc, 0, 0, 0); \
      a = __builtin_amdgcn_mfma_f32_16x16x32_f16(K1, Qf[nt][1], a, 0, 0, 0);  \
      St[nt] = a;                                                             \
    }                                                                         \
    f16x4 Pf[4];                                                              \
    _Pragma("unroll")                                                         \
    for (int nt = 0; nt < 4; ++nt) {                                          \
      float e0 = __builtin_amdgcn_exp2f(St[nt].x);                            \
      float e1 = __builtin_amdgcn_exp2f(St[nt].y);                            \
      float e2 = __builtin_amdgcn_exp2f(St[nt].z);                            \
      float e3 = __builtin_amdgcn_exp2f(St[nt].w);                            \
      ls[nt] += (e0 + e1) + (e2 + e3);                                        \
      auto lo = __builtin_amdgcn_cvt_pkrtz(e0, e1);                           \
      auto hi = __builtin_amdgcn_cvt_pkrtz(e2, e3);                           \
      f16x4 p;                                                                \
      ((decltype(lo)*)&p)[0] = lo;                                            \
      ((decltype(lo)*)&p)[1] = hi;                                            \
      Pf[nt] = p;                                                             \
    }                                                                         \
    _Pragma("unroll")                                                         \
    for (int nt = 0; nt < 4; ++nt)                                            \
      _Pragma("unroll")                                                       \
      for (int dt = 0; dt < 4; ++dt)                                          \
        Oa[nt][dt] = __builtin_amdgcn_mfma_f32_16x16x16f16(Pf[nt], Vf[dt],    \
                                                           Oa[nt][dt], 0, 0, 0); \
  }

#pragma unroll 1
  for (int g = 0; g < 10; ++g) {
    const int k0 = 3 * g;
    FA_BODY(0, 2, k0 + 2, "8")   // kt = 3g+0: read buf0, stage kt+2 -> buf2
    FA_BODY(1, 0, k0 + 3, "8")   // kt = 3g+1: read buf1, stage -> buf0
    FA_BODY(2, 1, k0 + 4, "8")   // kt = 3g+2: read buf2, stage -> buf1
  }
  FA_BODY(0, 2, 32, "4")         // kt = 30: no stage, tile30 landed
  FA_BODY(1, 0, 32, "0")         // kt = 31: drain

#undef FA_BODY

  // ---- epilogue: row sums + O tree-reduction (staging LDS reused) ----
#pragma unroll
  for (int nt = 0; nt < 4; ++nt) {
    float l = ls[nt];
    l += __shfl_xor(l, 16, 64);
    l += __shfl_xor(l, 32, 64);
    ls[nt] = l;
  }
  __syncthreads();              // all waves done with staging LDS
  if (qd == 0) {
#pragma unroll
    for (int nt = 0; nt < 4; ++nt) Lred[w][16 * nt + lq] = ls[nt];
  }
  float* OsA = (float*)smem;
  float* OsB = (float*)(smem + 16896);
  float* Os = (w & 2) ? OsB : OsA;
  if (!(w & 1)) {
#pragma unroll
    for (int nt = 0; nt < 4; ++nt)
#pragma unroll
      for (int dt = 0; dt < 4; ++dt)
#pragma unroll
        for (int r = 0; r < 4; ++r)
          Os[(16 * nt + 4 * qd + r) * 66 + 16 * dt + lq] = Oa[nt][dt][r];
  }
  __syncthreads();
  if (w & 1) {
#pragma unroll
    for (int nt = 0; nt < 4; ++nt)
#pragma unroll
      for (int dt = 0; dt < 4; ++dt)
#pragma unroll
        for (int r = 0; r < 4; ++r)
          Os[(16 * nt + 4 * qd + r) * 66 + 16 * dt + lq] += Oa[nt][dt][r];
  }
  __syncthreads();

  float* og = out + base + (size_t)qt * 64 * Dc;
#pragma unroll
  for (int r = 0; r < 16; ++r) {
    int row = 16 * w + r;
    float l = Lred[0][row] + Lred[1][row] + Lred[2][row] + Lred[3][row];
    float vo = OsA[row * 66 + lane] + OsB[row * 66 + lane];
    og[(size_t)row * Dc + lane] = vo / l;
  }
}

extern "C" void kernel_launch(void* const* d_in, const int* in_sizes, int n_in,
                              void* d_out, int out_size, void* d_ws, size_t ws_size,
                              hipStream_t stream) {
  const float* q    = (const float*)d_in[0];
  const float* k    = (const float*)d_in[1];
  const float* v    = (const float*)d_in[2];
  const float* temp = (const float*)d_in[3];
  float* out = (float*)d_out;

  f16* kh = (f16*)d_ws;          // 8.4 MB
  f16* vt = kh + NE;             // 8.4 MB

  prep<<<dim3(Bc * Hc * (Sc / 64)), dim3(256), 0, stream>>>(k, v, temp, kh, vt);
  fa13<<<dim3(Bc * Hc * (Sc / 64)), dim3(256), 0, stream>>>(q, kh, vt, out);
}

// Round 9
// 211.561 us; speedup vs baseline: 1.2028x; 1.2028x over previous
//
#include <hip/hip_runtime.h>
#include <stdint.h>

// Attention B=2,H=16,S=2048,D=64 fp32. Round 14 (resubmit after infra
// timeout): triple-buffer with a SINGLE shared set of running DMA pointers
// -> the depth-2 prefetch pipeline of r13 without its register blow-up.
//
// r13 post-mortem: 170us, FETCH 168MB / WRITE 206MB = scratch spill #3.
// Mechanism isolated: each of the 3 unrolled bodies called stage(kt,...)
// with a runtime kt -> LLVM strength-reduced PER BODY -> 3x4 running
// pointers (24 VGPRs) of induction state vs r10's ~8. Spill history:
// r9 cap too low; r11 explicit cross-iter regs; r12 addr-calc at peak
// pressure; r13 per-body strength reduction. Fix here: ONE set of 4
// running pointers (kp0,kp1,vp0,vp1 = 8 VGPRs), shared by prologue and
// all bodies, advanced +tile once per body; bodies never see kt. LDS
// destinations are compile-time per body. No in-loop guard (tail peeled).
//
// Pipeline (unchanged from r13's intent):
//  - 3 buffers/wave (3 x [2KB K + 2KB V] = 12KB/wave, 48KB/block).
//  - Prologue stages tiles 0,1. Body kt: stage(kt+2) into buf (kt+2)%3 ==
//    (kt-1)%3 (read in body kt-1; those ds_reads retired before body kt-1's
//    MFMAs issued => WAR-safe, NO lgkm wait -- r10's per-iter lgkmcnt(0)
//    drain is DELETED). Then vmcnt(8): retires tile kt, whose DMA was
//    issued 2 bodies (~1200cy) ago -> wait ~always free. Then ds_reads,
//    QK -> exp2 -> PV, identical to r10. Tail: vmcnt(4), vmcnt(0).
//  - No barrier until epilogue. Waves free-run (m114 co-scheduling).
//
// Per-wave LDS layouts (unchanged):
//   K [16 rows=keys][8 slots of 16B]: row r slot s holds d-octet s^(r&7)
//   V [64 rows=d][2 slots of 16B]:    row d slot s holds key-chunk s^((d>>2)&1)
// Swizzles applied on the GLOBAL gather side of the DMA; fragment reads are
// <=2-way banked (free, m136).

typedef _Float16 f16;
typedef __attribute__((ext_vector_type(4))) _Float16 f16x4;
typedef __attribute__((ext_vector_type(8))) _Float16 f16x8;
typedef __attribute__((ext_vector_type(4))) float f32x4;

constexpr int Bc = 2, Hc = 16, Sc = 2048, Dc = 64;
constexpr size_t NE = (size_t)Bc * Hc * Sc * Dc;

__device__ inline void gld_lds16(const f16* g, f16* l) {
  __builtin_amdgcn_global_load_lds(
      (const __attribute__((address_space(1))) unsigned int*)g,
      (__attribute__((address_space(3))) unsigned int*)l, 16, 0, 0);
}

// ---------------- prep: K*scale -> f16; V -> f16 transposed (unchanged) ---
__global__ __launch_bounds__(256)
void prep(const float* __restrict__ kp, const float* __restrict__ vp,
          const float* __restrict__ temp,
          f16* __restrict__ kh, f16* __restrict__ vt) {
  const int tid = threadIdx.x;
  const int bh = blockIdx.x & 31;
  const int st = blockIdx.x >> 5;
  const float ksc = 1.44269504088896340736f / (temp[0] * 8.0f);

  const size_t base = (size_t)bh * Sc * Dc + (size_t)st * 64 * Dc;
  const float* kg = kp + base;
  f16* khg = kh + base;
#pragma unroll
  for (int i = 0; i < 4; ++i) {
    int f = tid + (i << 8);
    f32x4 a = *(const f32x4*)(kg + f * 4);
    *(f16x4*)(khg + f * 4) = (f16x4){(f16)(a.x * ksc), (f16)(a.y * ksc),
                                     (f16)(a.z * ksc), (f16)(a.w * ksc)};
  }
  const int sb = tid & 15, db = tid >> 4;
  const float* vg = vp + base;
  f32x4 r0 = *(const f32x4*)(vg + (4 * sb + 0) * Dc + 4 * db);
  f32x4 r1 = *(const f32x4*)(vg + (4 * sb + 1) * Dc + 4 * db);
  f32x4 r2 = *(const f32x4*)(vg + (4 * sb + 2) * Dc + 4 * db);
  f32x4 r3 = *(const f32x4*)(vg + (4 * sb + 3) * Dc + 4 * db);
  f16* vtg = vt + (size_t)bh * Dc * Sc + (size_t)st * 64 + 4 * sb;
  *(f16x4*)(vtg + (size_t)(4 * db + 0) * Sc) = (f16x4){(f16)r0.x, (f16)r1.x, (f16)r2.x, (f16)r3.x};
  *(f16x4*)(vtg + (size_t)(4 * db + 1) * Sc) = (f16x4){(f16)r0.y, (f16)r1.y, (f16)r2.y, (f16)r3.y};
  *(f16x4*)(vtg + (size_t)(4 * db + 2) * Sc) = (f16x4){(f16)r0.z, (f16)r1.z, (f16)r2.z, (f16)r3.z};
  *(f16x4*)(vtg + (size_t)(4 * db + 3) * Sc) = (f16x4){(f16)r0.w, (f16)r1.w, (f16)r2.w, (f16)r3.w};
}

// ---------------- fa14: triple-buffer, shared running pointers ------------
__global__ __launch_bounds__(256, 3)
void fa14(const float* __restrict__ qp, const f16* __restrict__ kh,
          const f16* __restrict__ vt, float* __restrict__ out) {
  // union: staging (4 waves x 3 bufs x [2KB K + 2KB V] = 48KB) /
  //        epilogue (2x 64x66 f32 = 33792B)
  __shared__ __align__(16) char smem[49152];
  __shared__ float Lred[4][64];

  const int tid = threadIdx.x, lane = tid & 63, w = tid >> 6;
  const int lq = lane & 15, qd = lane >> 4;
  const int L = blockIdx.x;
  const int bh = L & 31;                   // blockIdx%8 == bh%8 (XCD-affine)
  const int qt = L >> 5;

  const size_t base = (size_t)bh * Sc * Dc;

  // per-wave staging buffers (f16 units): 3 bufs x 1024 f16 per region
  f16* Kw = (f16*)smem + w * 3072;                 // [3][1024]
  f16* Vw = (f16*)(smem + 24576) + w * 3072;       // [3][1024]

  // ---- staging gather: ONE shared set of running pointers ----
  const int oct = (lane & 7) ^ ((lane >> 3) & 7);
  const int vd = lane >> 1;
  const int vc = (lane & 1) ^ ((lane >> 3) & 1);
  const f16* kp0 = kh + base + (size_t)(16 * w + (lane >> 3)) * 64 + oct * 8;
  const f16* kp1 = kp0 + 8 * 64;
  const f16* vp0 = vt + (size_t)bh * Dc * Sc + (size_t)vd * Sc + 16 * w + vc * 8;
  const f16* vp1 = vp0 + (size_t)32 * Sc;

  // stage next tile from the running pointers into buf B, then advance.
#define STG(B)                                                                \
  do {                                                                        \
    gld_lds16(kp0, Kw + (B) * 1024);                                          \
    gld_lds16(kp1, Kw + (B) * 1024 + 512);                                    \
    gld_lds16(vp0, Vw + (B) * 1024);                                          \
    gld_lds16(vp1, Vw + (B) * 1024 + 512);                                    \
    kp0 += 4096; kp1 += 4096; vp0 += 64; vp1 += 64;                           \
  } while (0)

  // ---- fragment LDS offsets (f16 units, constant per lane) ----
  const int koff0 = lq * 64 + ((qd) ^ (lq & 7)) * 8;
  const int koff1 = lq * 64 + ((4 + qd) ^ (lq & 7)) * 8;
  int voff[4];
#pragma unroll
  for (int dt = 0; dt < 4; ++dt)
    voff[dt] = (16 * dt + lq) * 16 + (((qd >> 1) ^ ((lq >> 2) & 1)) << 3) +
               (qd & 1) * 4;

  // ---- Q B-fragments (one-time packed cvt) ----
  const float* qg = qp + base + (size_t)qt * 64 * Dc;
  f16x8 Qf[4][2];
#pragma unroll
  for (int nt = 0; nt < 4; ++nt)
#pragma unroll
    for (int kc = 0; kc < 2; ++kc) {
      const float* p = qg + (16 * nt + lq) * Dc + 32 * kc + 8 * qd;
      f32x4 a = *(const f32x4*)p;
      f32x4 b = *(const f32x4*)(p + 4);
      auto p0 = __builtin_amdgcn_cvt_pkrtz(a.x, a.y);
      auto p1 = __builtin_amdgcn_cvt_pkrtz(a.z, a.w);
      auto p2 = __builtin_amdgcn_cvt_pkrtz(b.x, b.y);
      auto p3 = __builtin_amdgcn_cvt_pkrtz(b.z, b.w);
      f16x8 qf;
      ((decltype(p0)*)&qf)[0] = p0;
      ((decltype(p0)*)&qf)[1] = p1;
      ((decltype(p0)*)&qf)[2] = p2;
      ((decltype(p0)*)&qf)[3] = p3;
      Qf[nt][kc] = qf;
    }

  // pinned zero accumulator source (avoids 16 v_movs/iter re-zeroing C)
  float z0 = 0.f, z1 = 0.f, z2 = 0.f, z3 = 0.f;
  asm volatile("" : "+v"(z0), "+v"(z1), "+v"(z2), "+v"(z3));
  const f32x4 Zc = (f32x4){z0, z1, z2, z3};

  f32x4 Oa[4][4];
  float ls[4];
#pragma unroll
  for (int nt = 0; nt < 4; ++nt) {
    ls[nt] = 0.f;
#pragma unroll
    for (int dt = 0; dt < 4; ++dt) Oa[nt][dt] = (f32x4){0.f, 0.f, 0.f, 0.f};
  }

  STG(0);    // tile 0 -> buf 0
  STG(1);    // tile 1 -> buf 1

  // Body kt (BUF=kt%3): stage next (SBUF=(kt+2)%3, WAR-safe, no lgkm wait);
  // vmcnt(WN) retires tile kt (issued 2 bodies ago -> free); ds_read
  // fragments; QK -> exp -> PV. Identical to r10 downstream of the vmcnt.
#define FA_BODY(BUF, SBUF, DO_STG, WN)                                        \
  {                                                                           \
    if (DO_STG) STG(SBUF);                                                    \
    asm volatile("s_waitcnt vmcnt(" WN ")" ::: "memory");                     \
    const f16* KB = Kw + (BUF) * 1024;                                        \
    const f16* VB = Vw + (BUF) * 1024;                                        \
    f16x8 K0 = *(const f16x8*)(KB + koff0);                                   \
    f16x8 K1 = *(const f16x8*)(KB + koff1);                                   \
    f16x4 Vf[4];                                                              \
    _Pragma("unroll")                                                         \
    for (int dt = 0; dt < 4; ++dt) Vf[dt] = *(const f16x4*)(VB + voff[dt]);   \
    f32x4 St[4];                                                              \
    _Pragma("unroll")                                                         \
    for (int nt = 0; nt < 4; ++nt) {                                          \
      f32x4 a = __builtin_amdgcn_mfma_f32_16x16x32_f16(K0, Qf[nt][0], Zc, 0, 0, 0); \
      a = __builtin_amdgcn_mfma_f32_16x16x32_f16(K1, Qf[nt][1], a, 0, 0, 0);  \
      St[nt] = a;                                                             \
    }                                                                         \
    f16x4 Pf[4];                                                              \
    _Pragma("unroll")                                                         \
    for (int nt = 0; nt < 4; ++nt) {                                          \
      float e0 = __builtin_amdgcn_exp2f(St[nt].x);                            \
      float e1 = __builtin_amdgcn_exp2f(St[nt].y);                            \
      float e2 = __builtin_amdgcn_exp2f(St[nt].z);                            \
      float e3 = __builtin_amdgcn_exp2f(St[nt].w);                            \
      ls[nt] += (e0 + e1) + (e2 + e3);                                        \
      auto lo = __builtin_amdgcn_cvt_pkrtz(e0, e1);                           \
      auto hi = __builtin_amdgcn_cvt_pkrtz(e2, e3);                           \
      f16x4 p;                                                                \
      ((decltype(lo)*)&p)[0] = lo;                                            \
      ((decltype(lo)*)&p)[1] = hi;                                            \
      Pf[nt] = p;                                                             \
    }                                                                         \
    _Pragma("unroll")                                                         \
    for (int nt = 0; nt < 4; ++nt)                                            \
      _Pragma("unroll")                                                       \
      for (int dt = 0; dt < 4; ++dt)                                          \
        Oa[nt][dt] = __builtin_amdgcn_mfma_f32_16x16x16f16(Pf[nt], Vf[dt],    \
                                                           Oa[nt][dt], 0, 0, 0); \
  }

#pragma unroll 1
  for (int g = 0; g < 10; ++g) {         // bodies kt = 3g .. 3g+2 (0..29)
    FA_BODY(0, 2, 1, "8")
    FA_BODY(1, 0, 1, "8")
    FA_BODY(2, 1, 1, "8")
  }
  FA_BODY(0, 2, 0, "4")                  // kt=30: no stage; tile30 landed
  FA_BODY(1, 0, 0, "0")                  // kt=31: drain

#undef FA_BODY
#undef STG

  // ---- epilogue: row sums + O tree-reduction (staging LDS reused) ----
#pragma unroll
  for (int nt = 0; nt < 4; ++nt) {
    float l = ls[nt];
    l += __shfl_xor(l, 16, 64);
    l += __shfl_xor(l, 32, 64);
    ls[nt] = l;
  }
  __syncthreads();              // all waves done with staging LDS
  if (qd == 0) {
#pragma unroll
    for (int nt = 0; nt < 4; ++nt) Lred[w][16 * nt + lq] = ls[nt];
  }
  float* OsA = (float*)smem;
  float* OsB = (float*)(smem + 16896);
  float* Os = (w & 2) ? OsB : OsA;
  if (!(w & 1)) {
#pragma unroll
    for (int nt = 0; nt < 4; ++nt)
#pragma unroll
      for (int dt = 0; dt < 4; ++dt)
#pragma unroll
        for (int r = 0; r < 4; ++r)
          Os[(16 * nt + 4 * qd + r) * 66 + 16 * dt + lq] = Oa[nt][dt][r];
  }
  __syncthreads();
  if (w & 1) {
#pragma unroll
    for (int nt = 0; nt < 4; ++nt)
#pragma unroll
      for (int dt = 0; dt < 4; ++dt)
#pragma unroll
        for (int r = 0; r < 4; ++r)
          Os[(16 * nt + 4 * qd + r) * 66 + 16 * dt + lq] += Oa[nt][dt][r];
  }
  __syncthreads();

  float* og = out + base + (size_t)qt * 64 * Dc;
#pragma unroll
  for (int r = 0; r < 16; ++r) {
    int row = 16 * w + r;
    float l = Lred[0][row] + Lred[1][row] + Lred[2][row] + Lred[3][row];
    float vo = OsA[row * 66 + lane] + OsB[row * 66 + lane];
    og[(size_t)row * Dc + lane] = vo / l;
  }
}

extern "C" void kernel_launch(void* const* d_in, const int* in_sizes, int n_in,
                              void* d_out, int out_size, void* d_ws, size_t ws_size,
                              hipStream_t stream) {
  const float* q    = (const float*)d_in[0];
  const float* k    = (const float*)d_in[1];
  const float* v    = (const float*)d_in[2];
  const float* temp = (const float*)d_in[3];
  float* out = (float*)d_out;

  f16* kh = (f16*)d_ws;          // 8.4 MB
  f16* vt = kh + NE;             // 8.4 MB

  prep<<<dim3(Bc * Hc * (Sc / 64)), dim3(256), 0, stream>>>(k, v, temp, kh, vt);
  fa14<<<dim3(Bc * Hc * (Sc / 64)), dim3(256), 0, stream>>>(q, kh, vt, out);
}

// Round 10
// 171.902 us; speedup vs baseline: 1.4803x; 1.2307x over previous
//
#include <hip/hip_runtime.h>
#include <stdint.h>

// Attention B=2,H=16,S=2048,D=64 fp32. Round 15: r10's proven body with the
// q-tile HALVED (64->32 rows, NT=2) -> live set ~148->~100 regs -> 4 blocks/
// CU resident under __launch_bounds__(256,4), grid 2048 = 8/CU = two
// perfectly packed rounds. Attacks the occupancy tail, with a register DIET
// instead of register growth.
//
// r14 post-mortem: triple-buffer spilled for the 4th time (FETCH 82MB /
// WRITE 138MB) despite shared running pointers -- the 3-buffer rotation
// itself doesn't fit this live set at 3 waves/SIMD. Pipeline-deepening via
// LDS buffers is abandoned per pre-commitment.
//
// New theory (r10 counters): OccupancyPercent 22% == (12 waves + 4 waves)/2:
// grid 1024 = 4 blocks/CU work but only 3 resident (148 regs/wave) -> phase2
// runs ONE block/CU alone. Half the wall clock at 1/3 the parallelism, and
// never enough waves/SIMD (~2-3) to hide the body's 120-600cyc latencies
// (MfmaUtil 28 + VALU 31 = 59% busy, 40% wait).
//
// Fix: NT 4->2 (32 q-rows/block). Oa 64->32, Qf 32->16, St/Pf/ls halve.
// Everything else byte-identical to r10: same double-buffer staging (stage
// at top-of-pressure-valley into the buffer just read, lgkmcnt(0) then DMA),
// same vmcnt(4) discipline, same swizzles, same epilogue (scaled).
// K/V staging per body is unchanged (full 64-key tile); DMA issue rate per
// CU doubles but K/V re-reads hit L2 (FETCH counts HBM only).
//
// Per-wave LDS layouts (unchanged):
//   K [16 rows=keys][8 slots of 16B]: row r slot s holds d-octet s^(r&7)
//   V [64 rows=d][2 slots of 16B]:    row d slot s holds key-chunk s^((d>>2)&1)
// Swizzles applied on the GLOBAL gather side of the DMA; fragment reads are
// <=2-way banked (free, m136).

typedef _Float16 f16;
typedef __attribute__((ext_vector_type(4))) _Float16 f16x4;
typedef __attribute__((ext_vector_type(8))) _Float16 f16x8;
typedef __attribute__((ext_vector_type(4))) float f32x4;

constexpr int Bc = 2, Hc = 16, Sc = 2048, Dc = 64;
constexpr size_t NE = (size_t)Bc * Hc * Sc * Dc;

__device__ inline void gld_lds16(const f16* g, f16* l) {
  __builtin_amdgcn_global_load_lds(
      (const __attribute__((address_space(1))) unsigned int*)g,
      (__attribute__((address_space(3))) unsigned int*)l, 16, 0, 0);
}

// ---------------- prep: K*scale -> f16; V -> f16 transposed (unchanged) ---
__global__ __launch_bounds__(256)
void prep(const float* __restrict__ kp, const float* __restrict__ vp,
          const float* __restrict__ temp,
          f16* __restrict__ kh, f16* __restrict__ vt) {
  const int tid = threadIdx.x;
  const int bh = blockIdx.x & 31;
  const int st = blockIdx.x >> 5;
  const float ksc = 1.44269504088896340736f / (temp[0] * 8.0f);

  const size_t base = (size_t)bh * Sc * Dc + (size_t)st * 64 * Dc;
  const float* kg = kp + base;
  f16* khg = kh + base;
#pragma unroll
  for (int i = 0; i < 4; ++i) {
    int f = tid + (i << 8);
    f32x4 a = *(const f32x4*)(kg + f * 4);
    *(f16x4*)(khg + f * 4) = (f16x4){(f16)(a.x * ksc), (f16)(a.y * ksc),
                                     (f16)(a.z * ksc), (f16)(a.w * ksc)};
  }
  const int sb = tid & 15, db = tid >> 4;
  const float* vg = vp + base;
  f32x4 r0 = *(const f32x4*)(vg + (4 * sb + 0) * Dc + 4 * db);
  f32x4 r1 = *(const f32x4*)(vg + (4 * sb + 1) * Dc + 4 * db);
  f32x4 r2 = *(const f32x4*)(vg + (4 * sb + 2) * Dc + 4 * db);
  f32x4 r3 = *(const f32x4*)(vg + (4 * sb + 3) * Dc + 4 * db);
  f16* vtg = vt + (size_t)bh * Dc * Sc + (size_t)st * 64 + 4 * sb;
  *(f16x4*)(vtg + (size_t)(4 * db + 0) * Sc) = (f16x4){(f16)r0.x, (f16)r1.x, (f16)r2.x, (f16)r3.x};
  *(f16x4*)(vtg + (size_t)(4 * db + 1) * Sc) = (f16x4){(f16)r0.y, (f16)r1.y, (f16)r2.y, (f16)r3.y};
  *(f16x4*)(vtg + (size_t)(4 * db + 2) * Sc) = (f16x4){(f16)r0.z, (f16)r1.z, (f16)r2.z, (f16)r3.z};
  *(f16x4*)(vtg + (size_t)(4 * db + 3) * Sc) = (f16x4){(f16)r0.w, (f16)r1.w, (f16)r2.w, (f16)r3.w};
}

// ---------------- fa15: r10 body, NT=2 (32 q-rows), 4 blocks/CU -----------
__global__ __launch_bounds__(256, 4)
void fa15(const float* __restrict__ qp, const f16* __restrict__ kh,
          const f16* __restrict__ vt, float* __restrict__ out) {
  // union: staging (4 waves x [2KB K + 2KB V] x 2 buf = 32KB) /
  //        epilogue (2x 32x66 f32 = 16896B). Lred separate.
  __shared__ __align__(16) char smem[32768];
  __shared__ float Lred[4][32];

  const int tid = threadIdx.x, lane = tid & 63, w = tid >> 6;
  const int lq = lane & 15, qd = lane >> 4;
  const int L = blockIdx.x;
  const int bh = L & 31;                   // blockIdx%8 == bh%8 (XCD-affine)
  const int qt = L >> 5;                   // 0..63, 32-row q tiles

  const size_t base = (size_t)bh * Sc * Dc;

  // per-wave staging buffers (f16 units)
  f16* Kw = (f16*)smem + w * 2048;                 // [2][1024]
  f16* Vw = (f16*)(smem + 16384) + w * 2048;       // [2][1024]

  // ---- staging gather addresses (swizzle on the global side) ----
  const int oct = (lane & 7) ^ ((lane >> 3) & 7);
  const f16* kg0 = kh + base + (size_t)(16 * w + (lane >> 3)) * 64 + oct * 8;
  const f16* kg1 = kg0 + 8 * 64;
  const int vd = lane >> 1;
  const int vc = (lane & 1) ^ ((lane >> 3) & 1);
  const f16* vg0 = vt + (size_t)bh * Dc * Sc + (size_t)vd * Sc + 16 * w + vc * 8;
  const f16* vg1 = vg0 + (size_t)32 * Sc;

  auto stage = [&](int kt, int b) {
    gld_lds16(kg0 + (size_t)kt * 4096, Kw + b * 1024);
    gld_lds16(kg1 + (size_t)kt * 4096, Kw + b * 1024 + 512);
    gld_lds16(vg0 + kt * 64, Vw + b * 1024);
    gld_lds16(vg1 + kt * 64, Vw + b * 1024 + 512);
  };

  // ---- fragment LDS offsets (f16 units, constant per lane) ----
  const int koff0 = lq * 64 + ((qd) ^ (lq & 7)) * 8;
  const int koff1 = lq * 64 + ((4 + qd) ^ (lq & 7)) * 8;
  int voff[4];
#pragma unroll
  for (int dt = 0; dt < 4; ++dt)
    voff[dt] = (16 * dt + lq) * 16 + (((qd >> 1) ^ ((lq >> 2) & 1)) << 3) +
               (qd & 1) * 4;

  // ---- Q B-fragments (one-time packed cvt), 32 rows -> NT=2 ----
  const float* qg = qp + base + (size_t)qt * 32 * Dc;
  f16x8 Qf[2][2];
#pragma unroll
  for (int nt = 0; nt < 2; ++nt)
#pragma unroll
    for (int kc = 0; kc < 2; ++kc) {
      const float* p = qg + (16 * nt + lq) * Dc + 32 * kc + 8 * qd;
      f32x4 a = *(const f32x4*)p;
      f32x4 b = *(const f32x4*)(p + 4);
      auto p0 = __builtin_amdgcn_cvt_pkrtz(a.x, a.y);
      auto p1 = __builtin_amdgcn_cvt_pkrtz(a.z, a.w);
      auto p2 = __builtin_amdgcn_cvt_pkrtz(b.x, b.y);
      auto p3 = __builtin_amdgcn_cvt_pkrtz(b.z, b.w);
      f16x8 qf;
      ((decltype(p0)*)&qf)[0] = p0;
      ((decltype(p0)*)&qf)[1] = p1;
      ((decltype(p0)*)&qf)[2] = p2;
      ((decltype(p0)*)&qf)[3] = p3;
      Qf[nt][kc] = qf;
    }

  // pinned zero accumulator source (avoids v_movs/iter re-zeroing C)
  float z0 = 0.f, z1 = 0.f, z2 = 0.f, z3 = 0.f;
  asm volatile("" : "+v"(z0), "+v"(z1), "+v"(z2), "+v"(z3));
  const f32x4 Zc = (f32x4){z0, z1, z2, z3};

  f32x4 Oa[2][4];
  float ls[2];
#pragma unroll
  for (int nt = 0; nt < 2; ++nt) {
    ls[nt] = 0.f;
#pragma unroll
    for (int dt = 0; dt < 4; ++dt) Oa[nt][dt] = (f32x4){0.f, 0.f, 0.f, 0.f};
  }

  stage(0, 0);
  stage(1, 1);

  // Body kt (r10 discipline, NT=2): vmcnt(WN) [tile kt landed]; ds_read
  // K,V fragments from buf kt&1; lgkmcnt(0) [reads retired]; stage tile
  // kt+2 into the SAME buffer; QK -> exp2 -> PV.
#define FA_BODY(BUF, WN, STGKT)                                               \
  {                                                                           \
    asm volatile("s_waitcnt vmcnt(" WN ")" ::: "memory");                     \
    const f16* KB = Kw + (BUF) * 1024;                                        \
    const f16* VB = Vw + (BUF) * 1024;                                        \
    f16x8 K0 = *(const f16x8*)(KB + koff0);                                   \
    f16x8 K1 = *(const f16x8*)(KB + koff1);                                   \
    f16x4 Vf[4];                                                              \
    _Pragma("unroll")                                                         \
    for (int dt = 0; dt < 4; ++dt) Vf[dt] = *(const f16x4*)(VB + voff[dt]);   \
    asm volatile("s_waitcnt lgkmcnt(0)" ::: "memory");                        \
    if ((STGKT) < 32) stage((STGKT), (BUF));                                  \
    f32x4 St[2];                                                              \
    _Pragma("unroll")                                                         \
    for (int nt = 0; nt < 2; ++nt) {                                          \
      f32x4 a = __builtin_amdgcn_mfma_f32_16x16x32_f16(K0, Qf[nt][0], Zc, 0, 0, 0); \
      a = __builtin_amdgcn_mfma_f32_16x16x32_f16(K1, Qf[nt][1], a, 0, 0, 0);  \
      St[nt] = a;                                                             \
    }                                                                         \
    f16x4 Pf[2];                                                              \
    _Pragma("unroll")                                                         \
    for (int nt = 0; nt < 2; ++nt) {                                          \
      float e0 = __builtin_amdgcn_exp2f(St[nt].x);                            \
      float e1 = __builtin_amdgcn_exp2f(St[nt].y);                            \
      float e2 = __builtin_amdgcn_exp2f(St[nt].z);                            \
      float e3 = __builtin_amdgcn_exp2f(St[nt].w);                            \
      ls[nt] += (e0 + e1) + (e2 + e3);                                        \
      auto lo = __builtin_amdgcn_cvt_pkrtz(e0, e1);                           \
      auto hi = __builtin_amdgcn_cvt_pkrtz(e2, e3);                           \
      f16x4 p;                                                                \
      ((decltype(lo)*)&p)[0] = lo;                                            \
      ((decltype(lo)*)&p)[1] = hi;                                            \
      Pf[nt] = p;                                                             \
    }                                                                         \
    _Pragma("unroll")                                                         \
    for (int nt = 0; nt < 2; ++nt)                                            \
      _Pragma("unroll")                                                       \
      for (int dt = 0; dt < 4; ++dt)                                          \
        Oa[nt][dt] = __builtin_amdgcn_mfma_f32_16x16x16f16(Pf[nt], Vf[dt],    \
                                                           Oa[nt][dt], 0, 0, 0); \
  }

#pragma unroll 1
  for (int kt2 = 0; kt2 < 15; ++kt2) {
    FA_BODY(0, "4", 2 * kt2 + 2)
    FA_BODY(1, "4", 2 * kt2 + 3)
  }
  FA_BODY(0, "4", 32)   // kt=30, no further staging
  FA_BODY(1, "0", 32)   // kt=31, drain

#undef FA_BODY

  // ---- epilogue: row sums + O tree-reduction (staging LDS reused) ----
#pragma unroll
  for (int nt = 0; nt < 2; ++nt) {
    float l = ls[nt];
    l += __shfl_xor(l, 16, 64);
    l += __shfl_xor(l, 32, 64);
    ls[nt] = l;
  }
  __syncthreads();              // all waves done with staging LDS
  if (qd == 0) {
#pragma unroll
    for (int nt = 0; nt < 2; ++nt) Lred[w][16 * nt + lq] = ls[nt];
  }
  float* OsA = (float*)smem;                 // [32][66]
  float* OsB = (float*)(smem + 8448);        // [32][66]
  float* Os = (w & 2) ? OsB : OsA;
  if (!(w & 1)) {
#pragma unroll
    for (int nt = 0; nt < 2; ++nt)
#pragma unroll
      for (int dt = 0; dt < 4; ++dt)
#pragma unroll
        for (int r = 0; r < 4; ++r)
          Os[(16 * nt + 4 * qd + r) * 66 + 16 * dt + lq] = Oa[nt][dt][r];
  }
  __syncthreads();
  if (w & 1) {
#pragma unroll
    for (int nt = 0; nt < 2; ++nt)
#pragma unroll
      for (int dt = 0; dt < 4; ++dt)
#pragma unroll
        for (int r = 0; r < 4; ++r)
          Os[(16 * nt + 4 * qd + r) * 66 + 16 * dt + lq] += Oa[nt][dt][r];
  }
  __syncthreads();

  float* og = out + base + (size_t)qt * 32 * Dc;
#pragma unroll
  for (int r = 0; r < 8; ++r) {
    int row = 8 * w + r;
    float l = Lred[0][row] + Lred[1][row] + Lred[2][row] + Lred[3][row];
    float vo = OsA[row * 66 + lane] + OsB[row * 66 + lane];
    og[(size_t)row * Dc + lane] = vo / l;
  }
}

extern "C" void kernel_launch(void* const* d_in, const int* in_sizes, int n_in,
                              void* d_out, int out_size, void* d_ws, size_t ws_size,
                              hipStream_t stream) {
  const float* q    = (const float*)d_in[0];
  const float* k    = (const float*)d_in[1];
  const float* v    = (const float*)d_in[2];
  const float* temp = (const float*)d_in[3];
  float* out = (float*)d_out;

  f16* kh = (f16*)d_ws;          // 8.4 MB
  f16* vt = kh + NE;             // 8.4 MB

  prep<<<dim3(Bc * Hc * (Sc / 64)), dim3(256), 0, stream>>>(k, v, temp, kh, vt);
  fa15<<<dim3(Bc * Hc * (Sc / 32)), dim3(256), 0, stream>>>(q, kh, vt, out);
}

// Round 11
// 156.235 us; speedup vs baseline: 1.6288x; 1.1003x over previous
//
#include <hip/hip_runtime.h>
#include <stdint.h>

// Attention B=2,H=16,S=2048,D=64 fp32. Round 16: r10's proven body with ONE
// reorder -- QK MFMAs execute BETWEEN the ds_reads and the lgkmcnt(0)+stage,
// so the drain retires ~free. Zero new registers, zero new LDS.
//
// r15 post-mortem: NT=2 halved MFMA/block but left per-block staging cost
// unchanged -> staging tax doubled chip-wide, MfmaUtil 28->22.6, fa 95.4us.
// Occupancy (22->36.5%) couldn't pay for it. q-tile stays 64.
//
// r10's body order: vmcnt(4); ds_read x6; lgkmcnt(0) [~120cy wait on reads
// issued RIGHT above]; stage; QK; exp; PV. The drain is the last removable
// stall that needs no extra buffer (r11-r14: every added buffer/register
// spilled). Reorder: vmcnt(4); ds_read x6; QK (compiler's own precise lgkm
// wait covers only the K-reads -- DS returns in-order, K issued first);
// sched_barrier(0) [pin: hipcc hoists/sinks reg-only MFMA across asm,
// rule #18]; lgkmcnt(0) [V-reads had the whole QK section to finish ->
// ~free]; stage into the just-read buffer (WAR still proven by the drain);
// exp; PV. Pressure at the new stage site (Oa64+Qf32+St16+Vf8+addr~12=132)
// is BELOW r10's PV-site peak (~140): same live set, reordered.
//
// Everything else byte-identical to r10 (71.9us, MfmaUtil 28, no spill):
// wave-private double-buffered staging, counted vmcnt(4), no in-loop
// barriers, raw v_exp_f32, pinned-zero C, epilogue tree-reduction.
//
// Per-wave LDS layouts (unchanged):
//   K [16 rows=keys][8 slots of 16B]: row r slot s holds d-octet s^(r&7)
//   V [64 rows=d][2 slots of 16B]:    row d slot s holds key-chunk s^((d>>2)&1)
// Swizzles applied on the GLOBAL gather side of the DMA; fragment reads are
// <=2-way banked (free, m136).

typedef _Float16 f16;
typedef __attribute__((ext_vector_type(4))) _Float16 f16x4;
typedef __attribute__((ext_vector_type(8))) _Float16 f16x8;
typedef __attribute__((ext_vector_type(4))) float f32x4;

constexpr int Bc = 2, Hc = 16, Sc = 2048, Dc = 64;
constexpr size_t NE = (size_t)Bc * Hc * Sc * Dc;

__device__ inline void gld_lds16(const f16* g, f16* l) {
  __builtin_amdgcn_global_load_lds(
      (const __attribute__((address_space(1))) unsigned int*)g,
      (__attribute__((address_space(3))) unsigned int*)l, 16, 0, 0);
}

// ---------------- prep: K*scale -> f16; V -> f16 transposed (unchanged) ---
__global__ __launch_bounds__(256)
void prep(const float* __restrict__ kp, const float* __restrict__ vp,
          const float* __restrict__ temp,
          f16* __restrict__ kh, f16* __restrict__ vt) {
  const int tid = threadIdx.x;
  const int bh = blockIdx.x & 31;
  const int st = blockIdx.x >> 5;
  const float ksc = 1.44269504088896340736f / (temp[0] * 8.0f);

  const size_t base = (size_t)bh * Sc * Dc + (size_t)st * 64 * Dc;
  const float* kg = kp + base;
  f16* khg = kh + base;
#pragma unroll
  for (int i = 0; i < 4; ++i) {
    int f = tid + (i << 8);
    f32x4 a = *(const f32x4*)(kg + f * 4);
    *(f16x4*)(khg + f * 4) = (f16x4){(f16)(a.x * ksc), (f16)(a.y * ksc),
                                     (f16)(a.z * ksc), (f16)(a.w * ksc)};
  }
  const int sb = tid & 15, db = tid >> 4;
  const float* vg = vp + base;
  f32x4 r0 = *(const f32x4*)(vg + (4 * sb + 0) * Dc + 4 * db);
  f32x4 r1 = *(const f32x4*)(vg + (4 * sb + 1) * Dc + 4 * db);
  f32x4 r2 = *(const f32x4*)(vg + (4 * sb + 2) * Dc + 4 * db);
  f32x4 r3 = *(const f32x4*)(vg + (4 * sb + 3) * Dc + 4 * db);
  f16* vtg = vt + (size_t)bh * Dc * Sc + (size_t)st * 64 + 4 * sb;
  *(f16x4*)(vtg + (size_t)(4 * db + 0) * Sc) = (f16x4){(f16)r0.x, (f16)r1.x, (f16)r2.x, (f16)r3.x};
  *(f16x4*)(vtg + (size_t)(4 * db + 1) * Sc) = (f16x4){(f16)r0.y, (f16)r1.y, (f16)r2.y, (f16)r3.y};
  *(f16x4*)(vtg + (size_t)(4 * db + 2) * Sc) = (f16x4){(f16)r0.z, (f16)r1.z, (f16)r2.z, (f16)r3.z};
  *(f16x4*)(vtg + (size_t)(4 * db + 3) * Sc) = (f16x4){(f16)r0.w, (f16)r1.w, (f16)r2.w, (f16)r3.w};
}

// ---------------- fa16: r10 body, drain moved below QK --------------------
__global__ __launch_bounds__(256, 3)
void fa16(const float* __restrict__ qp, const f16* __restrict__ kh,
          const f16* __restrict__ vt, float* __restrict__ out) {
  // union: staging (4 waves x [2KB K + 2KB V] x 2 buf = 32KB) /
  //        epilogue (2x 64x66 f32 = 33792B)
  __shared__ __align__(16) char smem[33792];
  __shared__ float Lred[4][64];

  const int tid = threadIdx.x, lane = tid & 63, w = tid >> 6;
  const int lq = lane & 15, qd = lane >> 4;
  const int L = blockIdx.x;
  const int bh = L & 31;                   // blockIdx%8 == bh%8 (XCD-affine)
  const int qt = L >> 5;

  const size_t base = (size_t)bh * Sc * Dc;

  // per-wave staging buffers (f16 units)
  f16* Kw = (f16*)smem + w * 2048;                 // [2][1024]
  f16* Vw = (f16*)(smem + 16384) + w * 2048;       // [2][1024]

  // ---- staging gather addresses (swizzle on the global side) ----
  const int oct = (lane & 7) ^ ((lane >> 3) & 7);
  const f16* kg0 = kh + base + (size_t)(16 * w + (lane >> 3)) * 64 + oct * 8;
  const f16* kg1 = kg0 + 8 * 64;
  const int vd = lane >> 1;
  const int vc = (lane & 1) ^ ((lane >> 3) & 1);
  const f16* vg0 = vt + (size_t)bh * Dc * Sc + (size_t)vd * Sc + 16 * w + vc * 8;
  const f16* vg1 = vg0 + (size_t)32 * Sc;

  auto stage = [&](int kt, int b) {
    gld_lds16(kg0 + (size_t)kt * 4096, Kw + b * 1024);
    gld_lds16(kg1 + (size_t)kt * 4096, Kw + b * 1024 + 512);
    gld_lds16(vg0 + kt * 64, Vw + b * 1024);
    gld_lds16(vg1 + kt * 64, Vw + b * 1024 + 512);
  };

  // ---- fragment LDS offsets (f16 units, constant per lane) ----
  const int koff0 = lq * 64 + ((qd) ^ (lq & 7)) * 8;
  const int koff1 = lq * 64 + ((4 + qd) ^ (lq & 7)) * 8;
  int voff[4];
#pragma unroll
  for (int dt = 0; dt < 4; ++dt)
    voff[dt] = (16 * dt + lq) * 16 + (((qd >> 1) ^ ((lq >> 2) & 1)) << 3) +
               (qd & 1) * 4;

  // ---- Q B-fragments (one-time packed cvt) ----
  const float* qg = qp + base + (size_t)qt * 64 * Dc;
  f16x8 Qf[4][2];
#pragma unroll
  for (int nt = 0; nt < 4; ++nt)
#pragma unroll
    for (int kc = 0; kc < 2; ++kc) {
      const float* p = qg + (16 * nt + lq) * Dc + 32 * kc + 8 * qd;
      f32x4 a = *(const f32x4*)p;
      f32x4 b = *(const f32x4*)(p + 4);
      auto p0 = __builtin_amdgcn_cvt_pkrtz(a.x, a.y);
      auto p1 = __builtin_amdgcn_cvt_pkrtz(a.z, a.w);
      auto p2 = __builtin_amdgcn_cvt_pkrtz(b.x, b.y);
      auto p3 = __builtin_amdgcn_cvt_pkrtz(b.z, b.w);
      f16x8 qf;
      ((decltype(p0)*)&qf)[0] = p0;
      ((decltype(p0)*)&qf)[1] = p1;
      ((decltype(p0)*)&qf)[2] = p2;
      ((decltype(p0)*)&qf)[3] = p3;
      Qf[nt][kc] = qf;
    }

  // pinned zero accumulator source (avoids 16 v_movs/iter re-zeroing C)
  float z0 = 0.f, z1 = 0.f, z2 = 0.f, z3 = 0.f;
  asm volatile("" : "+v"(z0), "+v"(z1), "+v"(z2), "+v"(z3));
  const f32x4 Zc = (f32x4){z0, z1, z2, z3};

  f32x4 Oa[4][4];
  float ls[4];
#pragma unroll
  for (int nt = 0; nt < 4; ++nt) {
    ls[nt] = 0.f;
#pragma unroll
    for (int dt = 0; dt < 4; ++dt) Oa[nt][dt] = (f32x4){0.f, 0.f, 0.f, 0.f};
  }

  stage(0, 0);
  stage(1, 1);

  // Body kt: vmcnt(WN) [tile kt landed]; ds_read K,V; QK (precise compiler
  // lgkm wait covers K-reads only); SBAR pin; lgkmcnt(0) [V-reads finished
  // under QK -> ~free]; stage kt+2 into this buffer; exp; PV.
#define FA_BODY(BUF, WN, STGKT)                                               \
  {                                                                           \
    asm volatile("s_waitcnt vmcnt(" WN ")" ::: "memory");                     \
    const f16* KB = Kw + (BUF) * 1024;                                        \
    const f16* VB = Vw + (BUF) * 1024;                                        \
    f16x8 K0 = *(const f16x8*)(KB + koff0);                                   \
    f16x8 K1 = *(const f16x8*)(KB + koff1);                                   \
    f16x4 Vf[4];                                                              \
    _Pragma("unroll")                                                         \
    for (int dt = 0; dt < 4; ++dt) Vf[dt] = *(const f16x4*)(VB + voff[dt]);   \
    f32x4 St[4];                                                              \
    _Pragma("unroll")                                                         \
    for (int nt = 0; nt < 4; ++nt) {                                          \
      f32x4 a = __builtin_amdgcn_mfma_f32_16x16x32_f16(K0, Qf[nt][0], Zc, 0, 0, 0); \
      a = __builtin_amdgcn_mfma_f32_16x16x32_f16(K1, Qf[nt][1], a, 0, 0, 0);  \
      St[nt] = a;                                                             \
    }                                                                         \
    __builtin_amdgcn_sched_barrier(0);                                        \
    asm volatile("s_waitcnt lgkmcnt(0)" ::: "memory");                        \
    if ((STGKT) < 32) stage((STGKT), (BUF));                                  \
    f16x4 Pf[4];                                                              \
    _Pragma("unroll")                                                         \
    for (int nt = 0; nt < 4; ++nt) {                                          \
      float e0 = __builtin_amdgcn_exp2f(St[nt].x);                            \
      float e1 = __builtin_amdgcn_exp2f(St[nt].y);                            \
      float e2 = __builtin_amdgcn_exp2f(St[nt].z);                            \
      float e3 = __builtin_amdgcn_exp2f(St[nt].w);                            \
      ls[nt] += (e0 + e1) + (e2 + e3);                                        \
      auto lo = __builtin_amdgcn_cvt_pkrtz(e0, e1);                           \
      auto hi = __builtin_amdgcn_cvt_pkrtz(e2, e3);                           \
      f16x4 p;                                                                \
      ((decltype(lo)*)&p)[0] = lo;                                            \
      ((decltype(lo)*)&p)[1] = hi;                                            \
      Pf[nt] = p;                                                             \
    }                                                                         \
    _Pragma("unroll")                                                         \
    for (int nt = 0; nt < 4; ++nt)                                            \
      _Pragma("unroll")                                                       \
      for (int dt = 0; dt < 4; ++dt)                                          \
        Oa[nt][dt] = __builtin_amdgcn_mfma_f32_16x16x16f16(Pf[nt], Vf[dt],    \
                                                           Oa[nt][dt], 0, 0, 0); \
  }

#pragma unroll 1
  for (int kt2 = 0; kt2 < 15; ++kt2) {
    FA_BODY(0, "4", 2 * kt2 + 2)
    FA_BODY(1, "4", 2 * kt2 + 3)
  }
  FA_BODY(0, "4", 32)   // kt=30, no further staging
  FA_BODY(1, "0", 32)   // kt=31, drain

#undef FA_BODY

  // ---- epilogue: row sums + O tree-reduction (staging LDS reused) ----
#pragma unroll
  for (int nt = 0; nt < 4; ++nt) {
    float l = ls[nt];
    l += __shfl_xor(l, 16, 64);
    l += __shfl_xor(l, 32, 64);
    ls[nt] = l;
  }
  __syncthreads();              // all waves done with staging LDS
  if (qd == 0) {
#pragma unroll
    for (int nt = 0; nt < 4; ++nt) Lred[w][16 * nt + lq] = ls[nt];
  }
  float* OsA = (float*)smem;
  float* OsB = (float*)(smem + 16896);
  float* Os = (w & 2) ? OsB : OsA;
  if (!(w & 1)) {
#pragma unroll
    for (int nt = 0; nt < 4; ++nt)
#pragma unroll
      for (int dt = 0; dt < 4; ++dt)
#pragma unroll
        for (int r = 0; r < 4; ++r)
          Os[(16 * nt + 4 * qd + r) * 66 + 16 * dt + lq] = Oa[nt][dt][r];
  }
  __syncthreads();
  if (w & 1) {
#pragma unroll
    for (int nt = 0; nt < 4; ++nt)
#pragma unroll
      for (int dt = 0; dt < 4; ++dt)
#pragma unroll
        for (int r = 0; r < 4; ++r)
          Os[(16 * nt + 4 * qd + r) * 66 + 16 * dt + lq] += Oa[nt][dt][r];
  }
  __syncthreads();

  float* og = out + base + (size_t)qt * 64 * Dc;
#pragma unroll
  for (int r = 0; r < 16; ++r) {
    int row = 16 * w + r;
    float l = Lred[0][row] + Lred[1][row] + Lred[2][row] + Lred[3][row];
    float vo = OsA[row * 66 + lane] + OsB[row * 66 + lane];
    og[(size_t)row * Dc + lane] = vo / l;
  }
}

extern "C" void kernel_launch(void* const* d_in, const int* in_sizes, int n_in,
                              void* d_out, int out_size, void* d_ws, size_t ws_size,
                              hipStream_t stream) {
  const float* q    = (const float*)d_in[0];
  const float* k    = (const float*)d_in[1];
  const float* v    = (const float*)d_in[2];
  const float* temp = (const float*)d_in[3];
  float* out = (float*)d_out;

  f16* kh = (f16*)d_ws;          // 8.4 MB
  f16* vt = kh + NE;             // 8.4 MB

  prep<<<dim3(Bc * Hc * (Sc / 64)), dim3(256), 0, stream>>>(k, v, temp, kh, vt);
  fa16<<<dim3(Bc * Hc * (Sc / 64)), dim3(256), 0, stream>>>(q, kh, vt, out);
}

// Round 13
// 143.525 us; speedup vs baseline: 1.7730x; 1.0886x over previous
//
#include <hip/hip_runtime.h>
#include <stdint.h>

// Attention B=2,H=16,S=2048,D=64 fp32. Round 17 (resubmit after container
// failure): fa is BYTE-IDENTICAL to the proven r10 (71.9us, no spill). This
// round attacks the OTHER half of the wall clock: total-minus-fa has been a
// constant ~70-80us across all nine measured rounds, independent of fa --
// that residual is prep (+~5us launch). prep's V-transpose was the classic
// anti-pattern: 16 scattered 64B-chunk reads per instr, strided 128B-segment
// writes. Rewritten via LDS:
//   phase 1: fully-coalesced f32x4 row-major reads -> cvt f16 -> LDS [64][66]
//            (pad 66 -> transposed reads <=2-way banked, free per m136)
//   phase 2: transposed LDS reads -> coalesced 8B global writes (same layout
//            as before, byte-identical vt output)
// K-path unchanged (already coalesced). LDS 8.4KB -> prep occupancy unharmed.
//
// Decomposition probe: if total drops to ~100-115, prep was the gap; if
// total stays ~140, the residual is harness overhead and r10+thisprep is the
// practical roofline (declare next round).
//
// r16 post-mortem: drain-below-QK reorder raised peak pressure (K0/K1/Vf
// live through QK) -> small spill (FETCH 21MB) -> 78.1us. Sixth structural
// fa variant, sixth loss to r10. fa10 is settled; do not touch it.

typedef _Float16 f16;
typedef __attribute__((ext_vector_type(4))) _Float16 f16x4;
typedef __attribute__((ext_vector_type(8))) _Float16 f16x8;
typedef __attribute__((ext_vector_type(4))) float f32x4;

constexpr int Bc = 2, Hc = 16, Sc = 2048, Dc = 64;
constexpr size_t NE = (size_t)Bc * Hc * Sc * Dc;

__device__ inline void gld_lds16(const f16* g, f16* l) {
  __builtin_amdgcn_global_load_lds(
      (const __attribute__((address_space(1))) unsigned int*)g,
      (__attribute__((address_space(3))) unsigned int*)l, 16, 0, 0);
}

// ---------------- prep v2: K cvt coalesced; V transpose via LDS -----------
__global__ __launch_bounds__(256)
void prep(const float* __restrict__ kp, const float* __restrict__ vp,
          const float* __restrict__ temp,
          f16* __restrict__ kh, f16* __restrict__ vt) {
  __shared__ f16 Vl[64 * 66];                 // 8448B, pad 66 vs 64
  const int tid = threadIdx.x;
  const int bh = blockIdx.x & 31;
  const int st = blockIdx.x >> 5;
  const float ksc = 1.44269504088896340736f / (temp[0] * 8.0f);

  const size_t base = (size_t)bh * Sc * Dc + (size_t)st * 64 * Dc;

  // K: scale + cvt, fully coalesced (unchanged from r10's prep)
  const float* kg = kp + base;
  f16* khg = kh + base;
#pragma unroll
  for (int i = 0; i < 4; ++i) {
    int f = tid + (i << 8);
    f32x4 a = *(const f32x4*)(kg + f * 4);
    *(f16x4*)(khg + f * 4) = (f16x4){(f16)(a.x * ksc), (f16)(a.y * ksc),
                                     (f16)(a.z * ksc), (f16)(a.w * ksc)};
  }

  // V phase 1: coalesced row-major f32x4 reads -> f16 -> LDS [64][66]
  const float* vg = vp + base;
  const int vcb = tid & 15;                   // 4-float col block
  const int vr = tid >> 4;                    // row 0..15
#pragma unroll
  for (int i = 0; i < 4; ++i) {
    int row = vr + 16 * i;
    f32x4 a = *(const f32x4*)(vg + row * Dc + vcb * 4);
    *(f16x4*)(&Vl[row * 66 + vcb * 4]) =
        (f16x4){(f16)a.x, (f16)a.y, (f16)a.z, (f16)a.w};
  }
  __syncthreads();

  // V phase 2: transposed LDS reads (stride 66 -> <=2-way banked),
  // coalesced 8B global writes. Output byte-identical to r10's prep.
  const int sb = tid & 15, db = tid >> 4;
  f16* vtg = vt + (size_t)bh * Dc * Sc + (size_t)st * 64 + 4 * sb;
#pragma unroll
  for (int c = 0; c < 4; ++c) {
    int d = 4 * db + c;
    f16x4 v4 = (f16x4){Vl[(4 * sb + 0) * 66 + d], Vl[(4 * sb + 1) * 66 + d],
                       Vl[(4 * sb + 2) * 66 + d], Vl[(4 * sb + 3) * 66 + d]};
    *(f16x4*)(vtg + (size_t)d * Sc) = v4;
  }
}

// ---------------- fa10: BYTE-IDENTICAL to r10 (71.9us, proven) ------------
__global__ __launch_bounds__(256, 3)
void fa10(const float* __restrict__ qp, const f16* __restrict__ kh,
          const f16* __restrict__ vt, float* __restrict__ out) {
  // union: staging (4 waves x [2KB K + 2KB V] x 2 buf = 32KB) /
  //        epilogue (2x 64x66 f32 = 33792B)
  __shared__ __align__(16) char smem[33792];
  __shared__ float Lred[4][64];

  const int tid = threadIdx.x, lane = tid & 63, w = tid >> 6;
  const int lq = lane & 15, qd = lane >> 4;
  const int L = blockIdx.x;
  const int bh = L & 31;                   // blockIdx%8 == bh%8 (XCD-affine)
  const int qt = L >> 5;

  const size_t base = (size_t)bh * Sc * Dc;

  // per-wave staging buffers (f16 units)
  f16* Kw = (f16*)smem + w * 2048;                 // [2][1024]
  f16* Vw = (f16*)(smem + 16384) + w * 2048;       // [2][1024]

  // ---- staging gather addresses (swizzle on the global side) ----
  const int oct = (lane & 7) ^ ((lane >> 3) & 7);
  const f16* kg0 = kh + base + (size_t)(16 * w + (lane >> 3)) * 64 + oct * 8;
  const f16* kg1 = kg0 + 8 * 64;
  const int vd = lane >> 1;
  const int vc = (lane & 1) ^ ((lane >> 3) & 1);
  const f16* vg0 = vt + (size_t)bh * Dc * Sc + (size_t)vd * Sc + 16 * w + vc * 8;
  const f16* vg1 = vg0 + (size_t)32 * Sc;

  auto stage = [&](int kt, int b) {
    gld_lds16(kg0 + (size_t)kt * 4096, Kw + b * 1024);
    gld_lds16(kg1 + (size_t)kt * 4096, Kw + b * 1024 + 512);
    gld_lds16(vg0 + kt * 64, Vw + b * 1024);
    gld_lds16(vg1 + kt * 64, Vw + b * 1024 + 512);
  };

  // ---- fragment LDS offsets (f16 units, constant per lane) ----
  const int koff0 = lq * 64 + ((qd) ^ (lq & 7)) * 8;
  const int koff1 = lq * 64 + ((4 + qd) ^ (lq & 7)) * 8;
  int voff[4];
#pragma unroll
  for (int dt = 0; dt < 4; ++dt)
    voff[dt] = (16 * dt + lq) * 16 + (((qd >> 1) ^ ((lq >> 2) & 1)) << 3) +
               (qd & 1) * 4;

  // ---- Q B-fragments (one-time packed cvt) ----
  const float* qg = qp + base + (size_t)qt * 64 * Dc;
  f16x8 Qf[4][2];
#pragma unroll
  for (int nt = 0; nt < 4; ++nt)
#pragma unroll
    for (int kc = 0; kc < 2; ++kc) {
      const float* p = qg + (16 * nt + lq) * Dc + 32 * kc + 8 * qd;
      f32x4 a = *(const f32x4*)p;
      f32x4 b = *(const f32x4*)(p + 4);
      auto p0 = __builtin_amdgcn_cvt_pkrtz(a.x, a.y);
      auto p1 = __builtin_amdgcn_cvt_pkrtz(a.z, a.w);
      auto p2 = __builtin_amdgcn_cvt_pkrtz(b.x, b.y);
      auto p3 = __builtin_amdgcn_cvt_pkrtz(b.z, b.w);
      f16x8 qf;
      ((decltype(p0)*)&qf)[0] = p0;
      ((decltype(p0)*)&qf)[1] = p1;
      ((decltype(p0)*)&qf)[2] = p2;
      ((decltype(p0)*)&qf)[3] = p3;
      Qf[nt][kc] = qf;
    }

  // pinned zero accumulator source (avoids 16 v_movs/iter re-zeroing C)
  float z0 = 0.f, z1 = 0.f, z2 = 0.f, z3 = 0.f;
  asm volatile("" : "+v"(z0), "+v"(z1), "+v"(z2), "+v"(z3));
  const f32x4 Zc = (f32x4){z0, z1, z2, z3};

  f32x4 Oa[4][4];
  float ls[4];
#pragma unroll
  for (int nt = 0; nt < 4; ++nt) {
    ls[nt] = 0.f;
#pragma unroll
    for (int dt = 0; dt < 4; ++dt) Oa[nt][dt] = (f32x4){0.f, 0.f, 0.f, 0.f};
  }

  stage(0, 0);
  stage(1, 1);

#define FA_BODY(BUF, WN, STGKT)                                               \
  {                                                                           \
    asm volatile("s_waitcnt vmcnt(" WN ")" ::: "memory");                     \
    const f16* KB = Kw + (BUF) * 1024;                                        \
    const f16* VB = Vw + (BUF) * 1024;                                        \
    f16x8 K0 = *(const f16x8*)(KB + koff0);                                   \
    f16x8 K1 = *(const f16x8*)(KB + koff1);                                   \
    f16x4 Vf[4];                                                              \
    _Pragma("unroll")                                                         \
    for (int dt = 0; dt < 4; ++dt) Vf[dt] = *(const f16x4*)(VB + voff[dt]);   \
    asm volatile("s_waitcnt lgkmcnt(0)" ::: "memory");                        \
    if ((STGKT) < 32) stage((STGKT), (BUF));                                  \
    f32x4 St[4];                                                              \
    _Pragma("unroll")                                                         \
    for (int nt = 0; nt < 4; ++nt) {                                          \
      f32x4 a = __builtin_amdgcn_mfma_f32_16x16x32_f16(K0, Qf[nt][0], Zc, 0, 0, 0); \
      a = __builtin_amdgcn_mfma_f32_16x16x32_f16(K1, Qf[nt][1], a, 0, 0, 0);  \
      St[nt] = a;                                                             \
    }                                                                         \
    f16x4 Pf[4];                                                              \
    _Pragma("unroll")                                                         \
    for (int nt = 0; nt < 4; ++nt) {                                          \
      float e0 = __builtin_amdgcn_exp2f(St[nt].x);                            \
      float e1 = __builtin_amdgcn_exp2f(St[nt].y);                            \
      float e2 = __builtin_amdgcn_exp2f(St[nt].z);                            \
      float e3 = __builtin_amdgcn_exp2f(St[nt].w);                            \
      ls[nt] += (e0 + e1) + (e2 + e3);                                        \
      auto lo = __builtin_amdgcn_cvt_pkrtz(e0, e1);                           \
      auto hi = __builtin_amdgcn_cvt_pkrtz(e2, e3);                           \
      f16x4 p;                                                                \
      ((decltype(lo)*)&p)[0] = lo;                                            \
      ((decltype(lo)*)&p)[1] = hi;                                            \
      Pf[nt] = p;                                                             \
    }                                                                         \
    _Pragma("unroll")                                                         \
    for (int nt = 0; nt < 4; ++nt)                                            \
      _Pragma("unroll")                                                       \
      for (int dt = 0; dt < 4; ++dt)                                          \
        Oa[nt][dt] = __builtin_amdgcn_mfma_f32_16x16x16f16(Pf[nt], Vf[dt],    \
                                                           Oa[nt][dt], 0, 0, 0); \
  }

#pragma unroll 1
  for (int kt2 = 0; kt2 < 15; ++kt2) {
    FA_BODY(0, "4", 2 * kt2 + 2)
    FA_BODY(1, "4", 2 * kt2 + 3)
  }
  FA_BODY(0, "4", 32)   // kt=30, no further staging
  FA_BODY(1, "0", 32)   // kt=31, drain

#undef FA_BODY

  // ---- epilogue: row sums + O tree-reduction (staging LDS reused) ----
#pragma unroll
  for (int nt = 0; nt < 4; ++nt) {
    float l = ls[nt];
    l += __shfl_xor(l, 16, 64);
    l += __shfl_xor(l, 32, 64);
    ls[nt] = l;
  }
  __syncthreads();              // all waves done with staging LDS
  if (qd == 0) {
#pragma unroll
    for (int nt = 0; nt < 4; ++nt) Lred[w][16 * nt + lq] = ls[nt];
  }
  float* OsA = (float*)smem;
  float* OsB = (float*)(smem + 16896);
  float* Os = (w & 2) ? OsB : OsA;
  if (!(w & 1)) {
#pragma unroll
    for (int nt = 0; nt < 4; ++nt)
#pragma unroll
      for (int dt = 0; dt < 4; ++dt)
#pragma unroll
        for (int r = 0; r < 4; ++r)
          Os[(16 * nt + 4 * qd + r) * 66 + 16 * dt + lq] = Oa[nt][dt][r];
  }
  __syncthreads();
  if (w & 1) {
#pragma unroll
    for (int nt = 0; nt < 4; ++nt)
#pragma unroll
      for (int dt = 0; dt < 4; ++dt)
#pragma unroll
        for (int r = 0; r < 4; ++r)
          Os[(16 * nt + 4 * qd + r) * 66 + 16 * dt + lq] += Oa[nt][dt][r];
  }
  __syncthreads();

  float* og = out + base + (size_t)qt * 64 * Dc;
#pragma unroll
  for (int r = 0; r < 16; ++r) {
    int row = 16 * w + r;
    float l = Lred[0][row] + Lred[1][row] + Lred[2][row] + Lred[3][row];
    float vo = OsA[row * 66 + lane] + OsB[row * 66 + lane];
    og[(size_t)row * Dc + lane] = vo / l;
  }
}

extern "C" void kernel_launch(void* const* d_in, const int* in_sizes, int n_in,
                              void* d_out, int out_size, void* d_ws, size_t ws_size,
                              hipStream_t stream) {
  const float* q    = (const float*)d_in[0];
  const float* k    = (const float*)d_in[1];
  const float* v    = (const float*)d_in[2];
  const float* temp = (const float*)d_in[3];
  float* out = (float*)d_out;

  f16* kh = (f16*)d_ws;          // 8.4 MB
  f16* vt = kh + NE;             // 8.4 MB

  prep<<<dim3(Bc * Hc * (Sc / 64)), dim3(256), 0, stream>>>(k, v, temp, kh, vt);
  fa10<<<dim3(Bc * Hc * (Sc / 64)), dim3(256), 0, stream>>>(q, kh, vt, out);
}